// Round 1
// 1165.044 us; speedup vs baseline: 2.5717x; 2.5717x over previous
//
#include <hip/hip_runtime.h>
#include <hip/hip_bf16.h>

// TemporalAttention: B=8,T=128,N=64,K=8 heads,d=64,D=512
// H=[X|STE] [65536,1536] -> q,k,v = relu(H @ W^T + b) [65536,512] each
// per (head,b,n): S=q k^T/8, causal mask, softmax, O=P v
// out = relu(O @ Wo^T + bo)
// Round 4: replace plain-VALU attention (1975us, MfmaUtil=0, VALUBusy=26%)
// with MFMA flash-style attention: one block per (head,b,n), 4 waves,
// QK^T bf16 MFMA -> wave-parallel softmax (shfl_xor over 16-lane quad
// groups) -> P as fp16 in swizzled LDS -> PV fp16 MFMA. V transposed to
// [d][s] fp16 during staging (exact bf16->fp16). All LDS tiles
// XOR-swizzled so ds_read_b128 8-lane phases hit distinct bank quartets.
// GEMM stages 1 and 3 unchanged this round (one variable per round).

typedef __attribute__((ext_vector_type(8))) short short8;     // 8 x bf16/f16 frag
typedef __attribute__((ext_vector_type(8))) _Float16 half8;   // 8 x f16 for MFMA
typedef __attribute__((ext_vector_type(4))) float floatx4;    // MFMA acc / 16B fp32 ld
typedef __attribute__((ext_vector_type(4))) unsigned int uintx4; // 16B ld/st

static __device__ __forceinline__ ushort f2b(float f) {
  __hip_bfloat16 h = __float2bfloat16(f);
  return __builtin_bit_cast(ushort, h);
}
static __device__ __forceinline__ ushort f2h(float f) {
  _Float16 h = (_Float16)f;
  return __builtin_bit_cast(ushort, h);
}
// exact bf16 -> fp32 unpack from a packed uint (2 bf16)
static __device__ __forceinline__ float blo(unsigned int w) {
  return __builtin_bit_cast(float, w << 16);
}
static __device__ __forceinline__ float bhi(unsigned int w) {
  return __builtin_bit_cast(float, w & 0xffff0000u);
}
// load 8 consecutive fp32, convert to 8 packed bf16 (2 x dwordx4 loads)
static __device__ __forceinline__ uintx4 cvt8(const float* __restrict__ p) {
  const floatx4 f0 = *(const floatx4*)(p);
  const floatx4 f1 = *(const floatx4*)(p + 4);
  uintx4 r;
  r[0] = (unsigned int)f2b(f0[0]) | ((unsigned int)f2b(f0[1]) << 16);
  r[1] = (unsigned int)f2b(f0[2]) | ((unsigned int)f2b(f0[3]) << 16);
  r[2] = (unsigned int)f2b(f1[0]) | ((unsigned int)f2b(f1[1]) << 16);
  r[3] = (unsigned int)f2b(f1[2]) | ((unsigned int)f2b(f1[3]) << 16);
  return r;
}

// ---------------------------------------------------------------------------
// C[m, cbase+o] = relu(sum_c A[m,c] * W[o,c] + bias[o]),  A,W K-contiguous.
// (unchanged from Round 3 — verified passing)
// ---------------------------------------------------------------------------
template<int KDIM, bool CONCAT, bool TRIPLE, bool A_BF16, bool OUT_F32>
__global__ __launch_bounds__(256, 2)
void gemm_relu_bt(const void* __restrict__ A0v, const void* __restrict__ A1v,
                  const float* __restrict__ W0, const float* __restrict__ W1,
                  const float* __restrict__ W2,
                  const float* __restrict__ bias0, const float* __restrict__ bias1,
                  const float* __restrict__ bias2,
                  void* __restrict__ Cv, int ldc)
{
  __shared__ ushort As[128 * 72];   // stride 72 bf16 = 144 B (16B aligned)
  __shared__ ushort Bs[128 * 72];

  const int tn = blockIdx.x, tm = blockIdx.y;
  const int tid = threadIdx.x;
  const int wave = tid >> 6, lane = tid & 63;
  const int quad = lane >> 4, lid = lane & 15;
  const int wm = wave >> 1, wn = wave & 1;

  const float* W; const float* bias; int nbase, cbase;
  if (TRIPLE) {
    const int seg = tn >> 2;
    W    = (seg == 0) ? W0 : (seg == 1) ? W1 : W2;
    bias = (seg == 0) ? bias0 : (seg == 1) ? bias1 : bias2;
    nbase = (tn & 3) * 128;
    cbase = seg * 512;
  } else { W = W0; bias = bias0; nbase = tn * 128; cbase = 0; }

  floatx4 acc[4][4];
#pragma unroll
  for (int i = 0; i < 4; i++)
#pragma unroll
    for (int j = 0; j < 4; j++) acc[i][j] = (floatx4){0.f, 0.f, 0.f, 0.f};

  for (int kt = 0; kt < KDIM / 64; ++kt) {
#pragma unroll
    for (int i = 0; i < 4; i++) {
      const int cidx = tid + i * 256;
      const int row = cidx >> 3, ch = cidx & 7;
      const int k0 = kt * 64 + ch * 8;
      uintx4 va, vb;
      if (A_BF16) {
        const ushort* A0 = (const ushort*)A0v;
        va = *(const uintx4*)(A0 + (size_t)(tm * 128 + row) * KDIM + k0);
      } else if (CONCAT) {
        const int m = tm * 128 + row;
        if (k0 < 512) va = cvt8((const float*)A0v + (size_t)m * 512 + k0);
        else          va = cvt8((const float*)A1v + (size_t)m * 1024 + (k0 - 512));
      } else {
        va = cvt8((const float*)A0v + (size_t)(tm * 128 + row) * KDIM + k0);
      }
      vb = cvt8(W + (size_t)(nbase + row) * KDIM + k0);
      *(uintx4*)(&As[row * 72 + ch * 8]) = va;
      *(uintx4*)(&Bs[row * 72 + ch * 8]) = vb;
    }
    __syncthreads();
#pragma unroll
    for (int ks = 0; ks < 2; ++ks) {
      short8 af[4], bfr[4];
#pragma unroll
      for (int t = 0; t < 4; t++) {
        af[t]  = *(const short8*)(&As[(wm * 64 + t * 16 + lid) * 72 + ks * 32 + quad * 8]);
        bfr[t] = *(const short8*)(&Bs[(wn * 64 + t * 16 + lid) * 72 + ks * 32 + quad * 8]);
      }
#pragma unroll
      for (int i = 0; i < 4; i++)
#pragma unroll
        for (int j = 0; j < 4; j++)
          acc[i][j] = __builtin_amdgcn_mfma_f32_16x16x32_bf16(af[i], bfr[j], acc[i][j], 0, 0, 0);
    }
    __syncthreads();
  }

#pragma unroll
  for (int j = 0; j < 4; j++) {
    const int ncol = nbase + wn * 64 + j * 16 + lid;
    const float bv = bias[ncol];
    const int cg = cbase + ncol;
#pragma unroll
    for (int i = 0; i < 4; i++) {
      const int mrow = tm * 128 + wm * 64 + i * 16 + quad * 4;
#pragma unroll
      for (int r = 0; r < 4; r++) {
        float v = acc[i][j][r] + bv;
        v = v > 0.f ? v : 0.f;
        if (OUT_F32) ((float*)Cv)[(size_t)(mrow + r) * ldc + cg] = v;
        else         ((ushort*)Cv)[(size_t)(mrow + r) * ldc + cg] = f2b(v);
      }
    }
  }
}

// ---------------------------------------------------------------------------
// MFMA flash-style attention. One block per (head,b,n); 4 waves, each wave
// owns 32 S-rows. LDS (64 KB -> 2 blocks/CU):
//   Ks: bf16 K [s=128][d=64],  128B rows of 8 16B slots,  slot ^= (s & 7)
//   Vt: f16  V^T [d=64][s=128], 256B rows of 16 16B slots, slot ^= (d & 15)
//   Ps: f16  P [t=128][s=128],  256B rows of 16 16B slots, slot ^= (t & 15)
// Swizzle keys chosen so consecutive-8-lane phases of ds_read_b128 hit 8
// distinct bank quartets (conflict-free reads; writes at worst 4-way).
// MFMA C-layout (verified m89/m91): col = lid, row = quad*4 + reg.
// ---------------------------------------------------------------------------
__global__ __launch_bounds__(256, 2)
void attn_mfma(const ushort* __restrict__ qkv, ushort* __restrict__ outb)
{
  __shared__ ushort Ks[128 * 64];    // 16 KB
  __shared__ ushort Vt[64 * 128];    // 16 KB
  __shared__ ushort Ps[128 * 128];   // 32 KB

  const int bx = blockIdx.x;
  const int head = bx >> 9;
  const int b = (bx >> 6) & 7;
  const int n = bx & 63;
  const int tid = threadIdx.x;
  const int wave = tid >> 6, lane = tid & 63;
  const int quad = lane >> 4, lid = lane & 15;

  char* KsB = (char*)Ks;
  char* VtB = (char*)Vt;
  char* PsB = (char*)Ps;

  // ---- stage K (bf16, swizzled) and V (transpose -> f16 Vt, swizzled)
  // 128 rows x 8 slots of 16B each; 4 chunks per thread per buffer.
#pragma unroll
  for (int i = 0; i < 4; i++) {
    const int idx = tid + i * 256;          // 0..1023
    const int s = idx >> 3, slot = idx & 7;
    const ushort* gb = qkv + ((size_t)((b * 128 + s) * 64 + n)) * 1536 + head * 64;
    const uintx4 kw = *(const uintx4*)(gb + 512 + slot * 8);
    *(uintx4*)(KsB + s * 128 + ((slot ^ (s & 7)) << 4)) = kw;
    const uintx4 vw = *(const uintx4*)(gb + 1024 + slot * 8);
#pragma unroll
    for (int j = 0; j < 4; j++) {
      const int d0 = slot * 8 + 2 * j;
      const int d1 = d0 + 1;
      *(ushort*)(VtB + d0 * 256 + (((s >> 3) ^ (d0 & 15)) << 4) + (s & 7) * 2) = f2h(blo(vw[j]));
      *(ushort*)(VtB + d1 * 256 + (((s >> 3) ^ (d1 & 15)) << 4) + (s & 7) * 2) = f2h(bhi(vw[j]));
    }
  }

  // ---- q fragments direct from global (A-frag: row = lid, k = ks*32+quad*8)
  short8 qf[2][2];
#pragma unroll
  for (int i = 0; i < 2; i++)
#pragma unroll
    for (int ks = 0; ks < 2; ks++) {
      const int t = wave * 32 + i * 16 + lid;
      qf[i][ks] = *(const short8*)(qkv + ((size_t)((b * 128 + t) * 64 + n)) * 1536
                                   + head * 64 + ks * 32 + quad * 8);
    }
  __syncthreads();

  // ---- S = q k^T (bf16 MFMA): rows wave*32..+32, cols 0..127
  floatx4 acc[2][8];
#pragma unroll
  for (int i = 0; i < 2; i++)
#pragma unroll
    for (int j = 0; j < 8; j++) acc[i][j] = (floatx4){0.f, 0.f, 0.f, 0.f};

#pragma unroll
  for (int ks = 0; ks < 2; ks++) {
#pragma unroll
    for (int j = 0; j < 8; j++) {
      const int srow = j * 16 + lid;
      const short8 kf = *(const short8*)(KsB + srow * 128
                                         + (((ks * 4 + quad) ^ (srow & 7)) << 4));
#pragma unroll
      for (int i = 0; i < 2; i++)
        acc[i][j] = __builtin_amdgcn_mfma_f32_16x16x32_bf16(qf[i][ks], kf, acc[i][j], 0, 0, 0);
    }
  }

  // ---- scale + causal mask + wave-parallel softmax; store P (f16) to LDS.
  // Row t = wave*32 + i*16 + quad*4 + r; the 16 lanes of a quad group hold
  // all 128 cols of that row (8 per lane) -> reduce in-register over j then
  // shfl_xor over {1,2,4,8} (stays inside the 16-lane group).
  float sum[2][4];
#pragma unroll
  for (int i = 0; i < 2; i++)
#pragma unroll
    for (int r = 0; r < 4; r++) {
      const int row = wave * 32 + i * 16 + quad * 4 + r;
      float m = -1e30f;
#pragma unroll
      for (int j = 0; j < 8; j++) {
        const int col = j * 16 + lid;
        float sv = acc[i][j][r] * 0.125f;
        sv = (col > row) ? -1e30f : sv;   // causal mask (exp -> 0, matches NEG semantics)
        acc[i][j][r] = sv;
        m = fmaxf(m, sv);
      }
      m = fmaxf(m, __shfl_xor(m, 1));
      m = fmaxf(m, __shfl_xor(m, 2));
      m = fmaxf(m, __shfl_xor(m, 4));
      m = fmaxf(m, __shfl_xor(m, 8));
      float s = 0.f;
#pragma unroll
      for (int j = 0; j < 8; j++) {
        const float p = __expf(acc[i][j][r] - m);
        s += p;
        const int col = j * 16 + lid;
        *(ushort*)(PsB + row * 256 + (((col >> 3) ^ (row & 15)) << 4) + (col & 7) * 2) = f2h(p);
      }
      s += __shfl_xor(s, 1);
      s += __shfl_xor(s, 2);
      s += __shfl_xor(s, 4);
      s += __shfl_xor(s, 8);
      sum[i][r] = s;
    }
  __syncthreads();   // cheap safety: P writes -> P reads (wave-local but ordered)

  // ---- O = P v (f16 MFMA): A = P rows (s-contig), B = V^T rows (s-contig)
  floatx4 acc2[2][4];
#pragma unroll
  for (int i = 0; i < 2; i++)
#pragma unroll
    for (int j2 = 0; j2 < 4; j2++) acc2[i][j2] = (floatx4){0.f, 0.f, 0.f, 0.f};

#pragma unroll
  for (int ks2 = 0; ks2 < 4; ks2++) {
    short8 pf[2];
#pragma unroll
    for (int i = 0; i < 2; i++) {
      const int row = wave * 32 + i * 16 + lid;
      pf[i] = *(const short8*)(PsB + row * 256 + (((ks2 * 4 + quad) ^ (row & 15)) << 4));
    }
#pragma unroll
    for (int j2 = 0; j2 < 4; j2++) {
      const int dd = j2 * 16 + lid;
      const short8 vf = *(const short8*)(VtB + dd * 256 + (((ks2 * 4 + quad) ^ (dd & 15)) << 4));
#pragma unroll
      for (int i = 0; i < 2; i++)
        acc2[i][j2] = __builtin_amdgcn_mfma_f32_16x16x32_f16(
            __builtin_bit_cast(half8, pf[i]), __builtin_bit_cast(half8, vf),
            acc2[i][j2], 0, 0, 0);
    }
  }

  // ---- normalize by row sum, write O (bf16 ws). acc2 rows use the same
  // (i,quad,r) mapping as sum[][] -> divide directly, no cross-lane needed.
#pragma unroll
  for (int i = 0; i < 2; i++)
#pragma unroll
    for (int r = 0; r < 4; r++) {
      const float inv = 1.f / sum[i][r];
      const int t = wave * 32 + i * 16 + quad * 4 + r;
      ushort* ob = outb + ((size_t)((b * 128 + t) * 64 + n)) * 512 + head * 64;
#pragma unroll
      for (int j2 = 0; j2 < 4; j2++)
        ob[j2 * 16 + lid] = f2b(acc2[i][j2][r] * inv);
    }
}

extern "C" void kernel_launch(void* const* d_in, const int* in_sizes, int n_in,
                              void* d_out, int out_size, void* d_ws, size_t ws_size,
                              hipStream_t stream) {
  const float* X   = (const float*)d_in[0];   // [8,128,64,512]   fp32
  const float* STE = (const float*)d_in[1];   // [8,128,64,1024]  fp32
  const float* Wq  = (const float*)d_in[2];   // [512,1536]       fp32
  const float* bq  = (const float*)d_in[3];
  const float* Wk  = (const float*)d_in[4];
  const float* bk  = (const float*)d_in[5];
  const float* Wv  = (const float*)d_in[6];
  const float* bv  = (const float*)d_in[7];
  const float* Wo  = (const float*)d_in[8];   // [512,512]        fp32
  const float* bo  = (const float*)d_in[9];
  float* out = (float*)d_out;                 // [8,128,64,512]   fp32

  ushort* qkv = (ushort*)d_ws;                       // [65536,1536] bf16, 201 MB
  ushort* att = qkv + (size_t)65536 * 1536;          // [65536,512]  bf16, 67 MB

  // 1) fused QKV projection + ReLU (fp32 in, bf16 ws out)
  gemm_relu_bt<1536, true, true, false, false><<<dim3(12, 512), 256, 0, stream>>>(
      X, STE, Wq, Wk, Wv, bq, bk, bv, qkv, 1536);
  // 2) causal attention per (head,b,n) — MFMA flash-style (bf16 ws in/out)
  attn_mfma<<<dim3(4096), 256, 0, stream>>>(qkv, att);
  // 3) output projection + ReLU (bf16 ws in, fp32 out)
  gemm_relu_bt<512, false, false, true, true><<<dim3(4, 512), 256, 0, stream>>>(
      att, nullptr, Wo, nullptr, nullptr, bo, nullptr, nullptr, out, 512);
}

// Round 2
// 970.026 us; speedup vs baseline: 3.0887x; 1.2010x over previous
//
#include <hip/hip_runtime.h>
#include <hip/hip_bf16.h>

// TemporalAttention: B=8,T=128,N=64,K=8 heads,d=64,D=512
// H=[X|STE] [65536,1536] -> q,k,v = relu(H @ W^T + b) [65536,512] each
// per (head,b,n): S=q k^T/8, causal mask, softmax, O=P v
// out = relu(O @ Wo^T + bo)
// Round 5: GEMMs rebuilt on the m97 structure. A bf16 prepass converts
// X|STE -> H bf16 [65536,1536] (LLC-resident: 201 MB < 256 MB) and the
// weights -> bf16, so both GEMMs stage via global_load_lds width=16 into
// LINEAR LDS with the XOR bank-swizzle applied by pre-swizzling the
// GLOBAL source col-slot and applying the same XOR on ds_read (rule 21).
// No VALU conversion in the GEMM inner loop. Attention kernel unchanged
// from Round 4 (verified passing).
// Workspace: qkv 201MB | H 201MB (att aliases H after GEMM1) | Wb 4.7MB |
// Wob 0.5MB  => ~408 MB total.

typedef __attribute__((ext_vector_type(8))) short short8;     // 8 x bf16/f16 frag
typedef __attribute__((ext_vector_type(8))) _Float16 half8;   // 8 x f16 for MFMA
typedef __attribute__((ext_vector_type(4))) float floatx4;    // MFMA acc / 16B fp32 ld
typedef __attribute__((ext_vector_type(4))) unsigned int uintx4; // 16B ld/st

static __device__ __forceinline__ ushort f2b(float f) {
  __hip_bfloat16 h = __float2bfloat16(f);
  return __builtin_bit_cast(ushort, h);
}
static __device__ __forceinline__ ushort f2h(float f) {
  _Float16 h = (_Float16)f;
  return __builtin_bit_cast(ushort, h);
}
// exact bf16 -> fp32 unpack from a packed uint (2 bf16)
static __device__ __forceinline__ float blo(unsigned int w) {
  return __builtin_bit_cast(float, w << 16);
}
static __device__ __forceinline__ float bhi(unsigned int w) {
  return __builtin_bit_cast(float, w & 0xffff0000u);
}
// load 8 consecutive fp32, convert to 8 packed bf16 (2 x dwordx4 loads)
static __device__ __forceinline__ uintx4 cvt8(const float* __restrict__ p) {
  const floatx4 f0 = *(const floatx4*)(p);
  const floatx4 f1 = *(const floatx4*)(p + 4);
  uintx4 r;
  r[0] = (unsigned int)f2b(f0[0]) | ((unsigned int)f2b(f0[1]) << 16);
  r[1] = (unsigned int)f2b(f0[2]) | ((unsigned int)f2b(f0[3]) << 16);
  r[2] = (unsigned int)f2b(f1[0]) | ((unsigned int)f2b(f1[1]) << 16);
  r[3] = (unsigned int)f2b(f1[2]) | ((unsigned int)f2b(f1[3]) << 16);
  return r;
}
// async global->LDS, 16B per lane; LDS dest must be WAVE-UNIFORM base
// (HW writes lane l at base + l*16), global addr is per-lane.
static __device__ __forceinline__ void gld_lds16(const ushort* g, ushort* l) {
  __builtin_amdgcn_global_load_lds(
      (const __attribute__((address_space(1))) void*)g,
      (__attribute__((address_space(3))) void*)l, 16, 0, 0);
}

// ---------------------------------------------------------------------------
// Prepass: fp32 -> bf16 for H = [X | STE] (row = 512 X cols + 1024 STE cols)
// and the four weight matrices. Memory-bound; 8 elems (2x dwordx4) / iter.
// Chunk map (1 chunk = 8 floats):
//   [0, 4194304)            X    -> H[m][ (c&63)*8 ]        (64 chunks/row)
//   [4194304, 12582912)     STE  -> H[m][ 512+(c2&127)*8 ]  (128 chunks/row)
//   [12582912, 12877824)    Wq,Wk,Wv -> Wb flat [3][512][1536]
//   [12877824, 12910592)    Wo   -> Wob flat [512][512]
// ---------------------------------------------------------------------------
__global__ __launch_bounds__(256)
void cvt_bf16_pass(const float* __restrict__ X, const float* __restrict__ STE,
                   const float* __restrict__ Wq, const float* __restrict__ Wk,
                   const float* __restrict__ Wv, const float* __restrict__ Wo,
                   ushort* __restrict__ H, ushort* __restrict__ Wb,
                   ushort* __restrict__ Wob)
{
  const int stride = gridDim.x * blockDim.x;
  for (int c = blockIdx.x * blockDim.x + threadIdx.x; c < 12910592; c += stride) {
    const float* src; ushort* dst;
    if (c < 4194304) {
      const int m = c >> 6, col = (c & 63) << 3;
      src = X + ((size_t)c << 3);
      dst = H + (size_t)m * 1536 + col;
    } else if (c < 12582912) {
      const int c2 = c - 4194304;
      const int m = c2 >> 7, col = (c2 & 127) << 3;
      src = STE + ((size_t)c2 << 3);
      dst = H + (size_t)m * 1536 + 512 + col;
    } else if (c < 12877824) {
      const int c3 = c - 12582912;                 // 98304 chunks per W
      const int w = c3 / 98304;
      const int r = c3 - w * 98304;
      const float* Ws = (w == 0) ? Wq : (w == 1) ? Wk : Wv;
      src = Ws + ((size_t)r << 3);
      dst = Wb + ((size_t)c3 << 3);
    } else {
      const int c4 = c - 12877824;
      src = Wo + ((size_t)c4 << 3);
      dst = Wob + ((size_t)c4 << 3);
    }
    *(uintx4*)dst = cvt8(src);
  }
}

// ---------------------------------------------------------------------------
// C[m, cbase+o] = relu(sum_c A[m,c] * W[o,c] + bias[o]); A,W bf16 K-contig.
// m97 structure: 128x128 tile, BK=64, 4 waves x (4x4) 16x16x32 bf16 MFMA,
// global_load_lds width=16 staging, linear LDS [128][64] bf16 (128 B rows).
// Bank swizzle: LDS[row][phys_slot] holds col-slot phys^(row&7); achieved by
// pre-swizzling the GLOBAL source col (gload_lds dest stays linear) and
// XOR-ing the same key on ds_read -> 8 distinct bank quartets per 16-lane
// phase (2-way aliasing = free, m136).
// TRIPLE: n-tiles 0..11 -> {Wq,Wk,Wv} x 4 tiles of 128; ldc=1536.
// ---------------------------------------------------------------------------
template<int KDIM, bool TRIPLE, bool OUT_F32>
__global__ __launch_bounds__(256, 2)
void gemm_bf16_async(const ushort* __restrict__ A, const ushort* __restrict__ Wall,
                     const float* __restrict__ b0, const float* __restrict__ b1,
                     const float* __restrict__ b2, void* __restrict__ Cv, int ldc)
{
  __shared__ ushort As[128 * 64];   // 16 KB, linear
  __shared__ ushort Bs[128 * 64];   // 16 KB, linear

  const int tn = blockIdx.x, tm = blockIdx.y;
  const int tid = threadIdx.x;
  const int wave = tid >> 6, lane = tid & 63;
  const int quad = lane >> 4, lid = lane & 15;
  const int wm = wave >> 1, wn = wave & 1;

  const ushort* W; const float* bias; int nbase, cbase;
  if (TRIPLE) {
    const int seg = tn >> 2;
    W = Wall + (size_t)seg * 512 * 1536;
    bias = (seg == 0) ? b0 : (seg == 1) ? b1 : b2;
    nbase = (tn & 3) * 128;
    cbase = seg * 512;
  } else { W = Wall; bias = b0; nbase = tn * 128; cbase = 0; }

  // staging geometry: wave-issue i writes LDS bytes [(wave*4+i)*1024, +1024):
  // lane l -> row (wave*4+i)*8 + (l>>3), phys slot l&7. Source col-slot =
  // phys ^ (row&7).
  const int rloc = lane >> 3, sphys = lane & 7;

  floatx4 acc[4][4];
#pragma unroll
  for (int i = 0; i < 4; i++)
#pragma unroll
    for (int j = 0; j < 4; j++) acc[i][j] = (floatx4){0.f, 0.f, 0.f, 0.f};

  const char* AsB = (const char*)As;
  const char* BsB = (const char*)Bs;

  for (int kt = 0; kt < KDIM / 64; ++kt) {
#pragma unroll
    for (int i = 0; i < 4; i++) {
      const int row = (wave * 4 + i) * 8 + rloc;
      const int slog = sphys ^ (row & 7);
      const int k0 = kt * 64 + slog * 8;
      gld_lds16(A + (size_t)(tm * 128 + row) * KDIM + k0, As + (wave * 4 + i) * 512);
      gld_lds16(W + (size_t)(nbase + row) * KDIM + k0,    Bs + (wave * 4 + i) * 512);
    }
    __syncthreads();   // compiler drains vmcnt before s_barrier -> tiles ready
#pragma unroll
    for (int ks = 0; ks < 2; ++ks) {
      short8 af[4], bfr[4];
#pragma unroll
      for (int t = 0; t < 4; t++) {
        const int ar = wm * 64 + t * 16 + lid;
        const int br = wn * 64 + t * 16 + lid;
        af[t]  = *(const short8*)(AsB + ar * 128 + (((ks * 4 + quad) ^ (ar & 7)) << 4));
        bfr[t] = *(const short8*)(BsB + br * 128 + (((ks * 4 + quad) ^ (br & 7)) << 4));
      }
#pragma unroll
      for (int i = 0; i < 4; i++)
#pragma unroll
        for (int j = 0; j < 4; j++)
          acc[i][j] = __builtin_amdgcn_mfma_f32_16x16x32_bf16(af[i], bfr[j], acc[i][j], 0, 0, 0);
    }
    __syncthreads();
  }

  // ---- epilogue: C row = quad*4+reg, col = lane&15 (verified m89/m91 layout)
#pragma unroll
  for (int j = 0; j < 4; j++) {
    const int ncol = nbase + wn * 64 + j * 16 + lid;
    const float bv = bias[ncol];
    const int cg = cbase + ncol;
#pragma unroll
    for (int i = 0; i < 4; i++) {
      const int mrow = tm * 128 + wm * 64 + i * 16 + quad * 4;
#pragma unroll
      for (int r = 0; r < 4; r++) {
        float v = acc[i][j][r] + bv;
        v = v > 0.f ? v : 0.f;
        if (OUT_F32) ((float*)Cv)[(size_t)(mrow + r) * ldc + cg] = v;
        else         ((ushort*)Cv)[(size_t)(mrow + r) * ldc + cg] = f2b(v);
      }
    }
  }
}

// ---------------------------------------------------------------------------
// MFMA flash-style attention (unchanged from Round 4 — verified passing).
// One block per (head,b,n); 4 waves, each wave owns 32 S-rows.
// ---------------------------------------------------------------------------
__global__ __launch_bounds__(256, 2)
void attn_mfma(const ushort* __restrict__ qkv, ushort* __restrict__ outb)
{
  __shared__ ushort Ks[128 * 64];    // 16 KB
  __shared__ ushort Vt[64 * 128];    // 16 KB
  __shared__ ushort Ps[128 * 128];   // 32 KB

  const int bx = blockIdx.x;
  const int head = bx >> 9;
  const int b = (bx >> 6) & 7;
  const int n = bx & 63;
  const int tid = threadIdx.x;
  const int wave = tid >> 6, lane = tid & 63;
  const int quad = lane >> 4, lid = lane & 15;

  char* KsB = (char*)Ks;
  char* VtB = (char*)Vt;
  char* PsB = (char*)Ps;

#pragma unroll
  for (int i = 0; i < 4; i++) {
    const int idx = tid + i * 256;          // 0..1023
    const int s = idx >> 3, slot = idx & 7;
    const ushort* gb = qkv + ((size_t)((b * 128 + s) * 64 + n)) * 1536 + head * 64;
    const uintx4 kw = *(const uintx4*)(gb + 512 + slot * 8);
    *(uintx4*)(KsB + s * 128 + ((slot ^ (s & 7)) << 4)) = kw;
    const uintx4 vw = *(const uintx4*)(gb + 1024 + slot * 8);
#pragma unroll
    for (int j = 0; j < 4; j++) {
      const int d0 = slot * 8 + 2 * j;
      const int d1 = d0 + 1;
      *(ushort*)(VtB + d0 * 256 + (((s >> 3) ^ (d0 & 15)) << 4) + (s & 7) * 2) = f2h(blo(vw[j]));
      *(ushort*)(VtB + d1 * 256 + (((s >> 3) ^ (d1 & 15)) << 4) + (s & 7) * 2) = f2h(bhi(vw[j]));
    }
  }

  short8 qf[2][2];
#pragma unroll
  for (int i = 0; i < 2; i++)
#pragma unroll
    for (int ks = 0; ks < 2; ks++) {
      const int t = wave * 32 + i * 16 + lid;
      qf[i][ks] = *(const short8*)(qkv + ((size_t)((b * 128 + t) * 64 + n)) * 1536
                                   + head * 64 + ks * 32 + quad * 8);
    }
  __syncthreads();

  floatx4 acc[2][8];
#pragma unroll
  for (int i = 0; i < 2; i++)
#pragma unroll
    for (int j = 0; j < 8; j++) acc[i][j] = (floatx4){0.f, 0.f, 0.f, 0.f};

#pragma unroll
  for (int ks = 0; ks < 2; ks++) {
#pragma unroll
    for (int j = 0; j < 8; j++) {
      const int srow = j * 16 + lid;
      const short8 kf = *(const short8*)(KsB + srow * 128
                                         + (((ks * 4 + quad) ^ (srow & 7)) << 4));
#pragma unroll
      for (int i = 0; i < 2; i++)
        acc[i][j] = __builtin_amdgcn_mfma_f32_16x16x32_bf16(qf[i][ks], kf, acc[i][j], 0, 0, 0);
    }
  }

  float sum[2][4];
#pragma unroll
  for (int i = 0; i < 2; i++)
#pragma unroll
    for (int r = 0; r < 4; r++) {
      const int row = wave * 32 + i * 16 + quad * 4 + r;
      float m = -1e30f;
#pragma unroll
      for (int j = 0; j < 8; j++) {
        const int col = j * 16 + lid;
        float sv = acc[i][j][r] * 0.125f;
        sv = (col > row) ? -1e30f : sv;   // causal mask (exp -> 0, matches NEG semantics)
        acc[i][j][r] = sv;
        m = fmaxf(m, sv);
      }
      m = fmaxf(m, __shfl_xor(m, 1));
      m = fmaxf(m, __shfl_xor(m, 2));
      m = fmaxf(m, __shfl_xor(m, 4));
      m = fmaxf(m, __shfl_xor(m, 8));
      float s = 0.f;
#pragma unroll
      for (int j = 0; j < 8; j++) {
        const float p = __expf(acc[i][j][r] - m);
        s += p;
        const int col = j * 16 + lid;
        *(ushort*)(PsB + row * 256 + (((col >> 3) ^ (row & 15)) << 4) + (col & 7) * 2) = f2h(p);
      }
      s += __shfl_xor(s, 1);
      s += __shfl_xor(s, 2);
      s += __shfl_xor(s, 4);
      s += __shfl_xor(s, 8);
      sum[i][r] = s;
    }
  __syncthreads();

  floatx4 acc2[2][4];
#pragma unroll
  for (int i = 0; i < 2; i++)
#pragma unroll
    for (int j2 = 0; j2 < 4; j2++) acc2[i][j2] = (floatx4){0.f, 0.f, 0.f, 0.f};

#pragma unroll
  for (int ks2 = 0; ks2 < 4; ks2++) {
    short8 pf[2];
#pragma unroll
    for (int i = 0; i < 2; i++) {
      const int row = wave * 32 + i * 16 + lid;
      pf[i] = *(const short8*)(PsB + row * 256 + (((ks2 * 4 + quad) ^ (row & 15)) << 4));
    }
#pragma unroll
    for (int j2 = 0; j2 < 4; j2++) {
      const int dd = j2 * 16 + lid;
      const short8 vf = *(const short8*)(VtB + dd * 256 + (((ks2 * 4 + quad) ^ (dd & 15)) << 4));
#pragma unroll
      for (int i = 0; i < 2; i++)
        acc2[i][j2] = __builtin_amdgcn_mfma_f32_16x16x32_f16(
            __builtin_bit_cast(half8, pf[i]), __builtin_bit_cast(half8, vf),
            acc2[i][j2], 0, 0, 0);
    }
  }

#pragma unroll
  for (int i = 0; i < 2; i++)
#pragma unroll
    for (int r = 0; r < 4; r++) {
      const float inv = 1.f / sum[i][r];
      const int t = wave * 32 + i * 16 + quad * 4 + r;
      ushort* ob = outb + ((size_t)((b * 128 + t) * 64 + n)) * 512 + head * 64;
#pragma unroll
      for (int j2 = 0; j2 < 4; j2++)
        ob[j2 * 16 + lid] = f2b(acc2[i][j2][r] * inv);
    }
}

extern "C" void kernel_launch(void* const* d_in, const int* in_sizes, int n_in,
                              void* d_out, int out_size, void* d_ws, size_t ws_size,
                              hipStream_t stream) {
  const float* X   = (const float*)d_in[0];   // [8,128,64,512]   fp32
  const float* STE = (const float*)d_in[1];   // [8,128,64,1024]  fp32
  const float* Wq  = (const float*)d_in[2];   // [512,1536]       fp32
  const float* bq  = (const float*)d_in[3];
  const float* Wk  = (const float*)d_in[4];
  const float* bk  = (const float*)d_in[5];
  const float* Wv  = (const float*)d_in[6];
  const float* bv  = (const float*)d_in[7];
  const float* Wo  = (const float*)d_in[8];   // [512,512]        fp32
  const float* bo  = (const float*)d_in[9];
  float* out = (float*)d_out;                 // [8,128,64,512]   fp32

  // workspace layout (~408 MB):
  ushort* qkv = (ushort*)d_ws;                       // [65536,1536] bf16, 201 MB
  ushort* H   = qkv + (size_t)65536 * 1536;          // [65536,1536] bf16, 201 MB
  ushort* att = H;                                   // [65536,512]  bf16 (aliases H:
                                                     //  H dead after GEMM1)
  ushort* Wb  = H + (size_t)65536 * 1536;            // [3,512,1536] bf16, 4.7 MB
  ushort* Wob = Wb + (size_t)3 * 512 * 1536;         // [512,512]    bf16, 0.5 MB

  // 0) fp32 -> bf16 prepass (H = [X|STE], weights)
  cvt_bf16_pass<<<2048, 256, 0, stream>>>(X, STE, Wq, Wk, Wv, Wo, H, Wb, Wob);
  // 1) fused QKV projection + ReLU (bf16 in, bf16 ws out), global_load_lds
  gemm_bf16_async<1536, true, false><<<dim3(12, 512), 256, 0, stream>>>(
      H, Wb, bq, bk, bv, qkv, 1536);
  // 2) causal attention per (head,b,n) — MFMA flash-style (bf16 ws in/out)
  attn_mfma<<<dim3(4096), 256, 0, stream>>>(qkv, att);
  // 3) output projection + ReLU (bf16 ws in, fp32 out), global_load_lds
  gemm_bf16_async<512, false, true><<<dim3(4, 512), 256, 0, stream>>>(
      att, Wob, bo, nullptr, nullptr, out, 512);
}